// Round 5
// baseline (321.788 us; speedup 1.0000x reference)
//
#include <hip/hip_runtime.h>
#include <stdint.h>

typedef unsigned short u16;
typedef __attribute__((ext_vector_type(8))) short bh8;   // 8 bf16 = 4 VGPR
typedef __attribute__((ext_vector_type(4))) float f4;    // MFMA acc

#define LOG2E 1.44269504088896f
#define QSCALE 0.18033688f   // 0.125 * log2(e), folded into Q at GEMM1 epilogue

__device__ inline u16 f2bf(float f) {
  union { float f; uint32_t u; } c; c.f = f;
  uint32_t u = c.u;
  return (u16)((u + 0x7fffu + ((u >> 16) & 1u)) >> 16);  // RNE
}

__device__ inline uint32_t pk2(float a, float b) {  // pack 2 fp32 -> 2 bf16 (RN)
  union { float f; uint32_t u; } ca, cb; ca.f = a; cb.f = b;
  return ((ca.u + 0x8000u) >> 16) | (((cb.u + 0x8000u) >> 16) << 16);
}

__device__ inline float fast_exp2(float x) {
#if __has_builtin(__builtin_amdgcn_exp2f)
  return __builtin_amdgcn_exp2f(x);
#else
  return exp2f(x);
#endif
}

#if __has_builtin(__builtin_amdgcn_global_load_lds)
#define GLD16(gp, lp) __builtin_amdgcn_global_load_lds( \
    (const __attribute__((address_space(1))) void*)(gp), \
    (__attribute__((address_space(3))) void*)(lp), 16, 0, 0)
#else
#define GLD16(gp, lp) do { *(bh8*)(lp) = *(const bh8*)(gp); } while (0)
#endif

// ---------------- convert / transpose ----------------

__global__ __launch_bounds__(256) void cvt_f32_bf16(const float* __restrict__ src,
                                                    u16* __restrict__ dst, int n4) {
  int i = blockIdx.x * 256 + threadIdx.x;
  if (i < n4) {
    float4 v = ((const float4*)src)[i];
    ushort4 o;
    o.x = f2bf(v.x); o.y = f2bf(v.y); o.z = f2bf(v.z); o.w = f2bf(v.w);
    ((ushort4*)dst)[i] = o;
  }
}

// src: K x N fp32 row-major -> dst: N x K bf16 row-major
__global__ __launch_bounds__(1024) void transpose_cvt(const float* __restrict__ src,
                                                      u16* __restrict__ dst, int K, int N) {
  __shared__ float tile[32][33];
  int n0 = blockIdx.x * 32, k0 = blockIdx.y * 32;
  int tx = threadIdx.x, ty = threadIdx.y;
  tile[ty][tx] = src[(size_t)(k0 + ty) * N + n0 + tx];
  __syncthreads();
  dst[(size_t)(n0 + ty) * K + k0 + tx] = f2bf(tile[tx][ty]);
}

// v [64][2048][64] bf16 -> vt [64][64][2048] bf16
__global__ __launch_bounds__(1024) void transpose_b16(const u16* __restrict__ src,
                                                      u16* __restrict__ dst) {
  __shared__ u16 t[32][33];
  int bh = blockIdx.z, l0 = blockIdx.y * 32, d0 = blockIdx.x * 32;
  int tx = threadIdx.x, ty = threadIdx.y;
  t[ty][tx] = src[((size_t)bh * 2048 + l0 + ty) * 64 + d0 + tx];
  __syncthreads();
  dst[((size_t)bh * 64 + d0 + ty) * 2048 + l0 + tx] = t[tx][ty];
}

// ---------------- GEMM mainloop (C = A @ Bt^T), 128x128 tile, BK=64 ----------------
__device__ inline void gemm_mainloop(const u16* __restrict__ A, const u16* __restrict__ Bt,
                                     int K, int m0, int n0,
                                     u16* As, u16* Bs, f4 acc[4][4]) {
  const int tid  = threadIdx.x;
  const int lane = tid & 63;
  const int quad = lane >> 4;
  const int ml   = lane & 15;
  const int wave = tid >> 6;
  const int wm   = (wave >> 1) * 64;
  const int wn   = (wave & 1) * 64;

#pragma unroll 1
  for (int k0 = 0; k0 < K; k0 += 64) {
#pragma unroll
    for (int r = 0; r < 4; ++r) {
      int chunk = r * 256 + tid;
      int row = chunk >> 3, cc = chunk & 7;
      int cg = cc ^ (row & 7);
      GLD16(A + (size_t)(m0 + row) * K + k0 + cg * 8, As + chunk * 8);
    }
#pragma unroll
    for (int r = 0; r < 4; ++r) {
      int chunk = r * 256 + tid;
      int row = chunk >> 3, cc = chunk & 7;
      int cg = cc ^ (row & 7);
      GLD16(Bt + (size_t)(n0 + row) * K + k0 + cg * 8, Bs + chunk * 8);
    }
    __syncthreads();
#pragma unroll
    for (int ks = 0; ks < 2; ++ks) {
      bh8 af[4], bfr[4];
      int cs = (ks * 4 + quad) ^ (ml & 7);
#pragma unroll
      for (int i = 0; i < 4; ++i) {
        int row = wm + i * 16 + ml;
        af[i] = *(const bh8*)(As + (row * 8 + cs) * 8);
      }
#pragma unroll
      for (int j = 0; j < 4; ++j) {
        int row = wn + j * 16 + ml;
        bfr[j] = *(const bh8*)(Bs + (row * 8 + cs) * 8);
      }
#pragma unroll
      for (int i = 0; i < 4; ++i)
#pragma unroll
        for (int j = 0; j < 4; ++j)
          acc[i][j] = __builtin_amdgcn_mfma_f32_16x16x32_bf16(af[i], bfr[j], acc[i][j], 0, 0, 0);
    }
    __syncthreads();
  }
}

// ---------------- GEMM1: qkv = x @ w_qkv + b ----------------
__global__ __launch_bounds__(256) void gemm_qkv(const u16* __restrict__ xb,
                                                const u16* __restrict__ wqt,
                                                const float* __restrict__ bqkv,
                                                u16* __restrict__ q, u16* __restrict__ k,
                                                u16* __restrict__ v) {
  __shared__ __align__(16) u16 smem[2 * 128 * 64];
  const f4 fzero = {0.f, 0.f, 0.f, 0.f};
  f4 acc[4][4];
#pragma unroll
  for (int i = 0; i < 4; ++i)
#pragma unroll
    for (int j = 0; j < 4; ++j) acc[i][j] = fzero;

  int m0 = blockIdx.y * 128, n0 = blockIdx.x * 128;
  gemm_mainloop(xb, wqt, 1024, m0, n0, smem, smem + 128 * 64, acc);

  const int lane = threadIdx.x & 63, wave = threadIdx.x >> 6;
  const int quad = lane >> 4, ml = lane & 15;
  const int wm = (wave >> 1) * 64, wn = (wave & 1) * 64;
  u16* dst = (n0 < 1024) ? q : ((n0 < 2048) ? k : v);
  float scale = (n0 < 1024) ? QSCALE : 1.0f;
#pragma unroll
  for (int j = 0; j < 4; ++j) {
    int nn = n0 + wn + j * 16 + ml;
    int h = (nn >> 6) & 15, d = nn & 63;
    float bias = bqkv[nn];
#pragma unroll
    for (int i = 0; i < 4; ++i) {
#pragma unroll
      for (int r = 0; r < 4; ++r) {
        int tok = m0 + wm + i * 16 + quad * 4 + r;
        int b = tok >> 11, l = tok & 2047;
        int bh = b * 16 + h;
        dst[((size_t)bh * 2048 + l) * 64 + d] = f2bf((acc[i][j][r] + bias) * scale);
      }
    }
  }
}

// ---------------- GEMM2: out = o @ w_out + b_out (fp32 out) ----------------
__global__ __launch_bounds__(256) void gemm_out(const u16* __restrict__ ob,
                                                const u16* __restrict__ wot,
                                                const float* __restrict__ bout,
                                                float* __restrict__ out) {
  __shared__ __align__(16) u16 smem[2 * 128 * 64];
  const f4 fzero = {0.f, 0.f, 0.f, 0.f};
  f4 acc[4][4];
#pragma unroll
  for (int i = 0; i < 4; ++i)
#pragma unroll
    for (int j = 0; j < 4; ++j) acc[i][j] = fzero;

  int m0 = blockIdx.y * 128, n0 = blockIdx.x * 128;
  gemm_mainloop(ob, wot, 1024, m0, n0, smem, smem + 128 * 64, acc);

  const int lane = threadIdx.x & 63, wave = threadIdx.x >> 6;
  const int quad = lane >> 4, ml = lane & 15;
  const int wm = (wave >> 1) * 64, wn = (wave & 1) * 64;
#pragma unroll
  for (int j = 0; j < 4; ++j) {
    int nn = n0 + wn + j * 16 + ml;
    float bias = bout[nn];
#pragma unroll
    for (int i = 0; i < 4; ++i)
#pragma unroll
      for (int r = 0; r < 4; ++r) {
        int tok = m0 + wm + i * 16 + quad * 4 + r;
        out[(size_t)tok * 1024 + nn] = acc[i][j][r] + bias;
      }
  }
}

// ---------------- flash attention v5: 2x2 wave split to cut LDS bandwidth ----------
// grid (16, 64): x = q-tile of 128 rows, y = bh. Wave (wq,wk): wq picks 64 q-rows,
// wk picks 32 of the 64 staged keys. Each wave: S^T = K·Q^T (operand-swapped MFMA,
// C-layout rows=keys so P packs to b64 LDS writes), p=exp2 (Q pre-scaled), private
// P[64q][32k] round-trip at the 4-lane/bank b64 floor, PV with K=32. O/l halves
// combined once in the epilogue through LDS. LDS bytes/block-iter ~3x lower than v4.
__global__ __launch_bounds__(256, 2) void attn(const u16* __restrict__ q,
                                               const u16* __restrict__ k,
                                               const u16* __restrict__ vt,
                                               u16* __restrict__ o) {
  __shared__ __align__(16) char smem[34304];
  u16* Ks = (u16*)smem;           // 8 KB: 64 key-rows x 64 d (8 chunks, XOR swizzle)
  u16* Vs = Ks + 4096;            // 8 KB: 64 d-rows x 64 keys (8 chunks, XOR swizzle)
  const int bh = blockIdx.y;
  const int b = bh >> 4, h = bh & 15;
  const int tid = threadIdx.x;
  const int wave = tid >> 6, lane = tid & 63;
  const int quad = lane >> 4, ml = lane & 15, m7 = ml & 7;
  const int wq = wave >> 1, wk = wave & 1;
  u16* Pw = Vs + 4096 + wave * 2048;  // 4 KB/wave: P[64 q][32 keys] bf16, b64-chunk swizzled
  const int q0 = blockIdx.x * 128 + wq * 64;
  const u16* qp = q + (size_t)bh * 2048 * 64;
  const u16* kp = k + (size_t)bh * 2048 * 64;
  const u16* vp = vt + (size_t)bh * 64 * 2048;
  const f4 fzero = {0.f, 0.f, 0.f, 0.f};

  // Q fragments (B-operand): B[k=d][n=q], resident across the whole K-loop
  bh8 qf[4][2];
#pragma unroll
  for (int nq = 0; nq < 4; ++nq)
#pragma unroll
    for (int ks = 0; ks < 2; ++ks)
      qf[nq][ks] = *(const bh8*)&qp[(size_t)(q0 + nq * 16 + ml) * 64 + ks * 32 + quad * 8];

  f4 oacc[4][4];
  float li[4] = {0.f, 0.f, 0.f, 0.f};
#pragma unroll
  for (int mq = 0; mq < 4; ++mq)
#pragma unroll
    for (int nd = 0; nd < 4; ++nd) oacc[mq][nd] = fzero;

  const int srow = tid >> 3, scc = tid & 7, scg = scc ^ (srow & 7);

#pragma unroll 1
  for (int kt = 0; kt < 2048; kt += 64) {
    // cooperative staging: K tile (64 keys x 64 d), V tile (64 d x 64 keys)
#pragma unroll
    for (int r = 0; r < 2; ++r) {
      int row = r * 32 + srow;
      GLD16(kp + (size_t)(kt + row) * 64 + scg * 8, Ks + (row * 8 + scc) * 8);
      GLD16(vp + (size_t)row * 2048 + kt + scg * 8, Vs + (row * 8 + scc) * 8);
    }
    __syncthreads();

    // S^T[key][q] = K·Q^T : A = K-frags (m=key), B = Q-frags (n=q)
    f4 s[2][4];
#pragma unroll
    for (int mk = 0; mk < 2; ++mk)
#pragma unroll
      for (int nq = 0; nq < 4; ++nq) s[mk][nq] = fzero;
#pragma unroll
    for (int ks = 0; ks < 2; ++ks) {
      int cs = (ks * 4 + quad) ^ m7;
      bh8 kf[2];
#pragma unroll
      for (int mk = 0; mk < 2; ++mk)
        kf[mk] = *(const bh8*)(Ks + ((wk * 32 + mk * 16 + ml) * 8 + cs) * 8);
#pragma unroll
      for (int mk = 0; mk < 2; ++mk)
#pragma unroll
        for (int nq = 0; nq < 4; ++nq)
          s[mk][nq] = __builtin_amdgcn_mfma_f32_16x16x32_bf16(kf[mk], qf[nq][ks], s[mk][nq], 0, 0, 0);
    }

    // p = exp2(s); accumulate fp32 row-sums; pack 4 keys -> b64 write into Pw[q][key]
#pragma unroll
    for (int mk = 0; mk < 2; ++mk) {
      int cw = ((mk * 4 + quad) ^ m7) * 4;  // chunk of 4 keys, swizzled by q-row&7 (=ml&7)
#pragma unroll
      for (int nq = 0; nq < 4; ++nq) {
        float p0 = fast_exp2(s[mk][nq][0]);
        float p1 = fast_exp2(s[mk][nq][1]);
        float p2 = fast_exp2(s[mk][nq][2]);
        float p3 = fast_exp2(s[mk][nq][3]);
        li[nq] += (p0 + p1) + (p2 + p3);
        uint2 w; w.x = pk2(p0, p1); w.y = pk2(p2, p3);
        *(uint2*)(Pw + (nq * 16 + ml) * 32 + cw) = w;
      }
    }

    // O += P·V (K=32, wave's own key strip)
    bh8 vf[4];
    int cv = (wk * 4 + quad) ^ m7;
#pragma unroll
    for (int nd = 0; nd < 4; ++nd)
      vf[nd] = *(const bh8*)(Vs + ((nd * 16 + ml) * 8 + cv) * 8);
    int c0 = ((quad * 2) ^ m7) * 4;
    int c1 = ((quad * 2 + 1) ^ m7) * 4;
#pragma unroll
    for (int mq = 0; mq < 4; ++mq) {
      uint2 a = *(const uint2*)(Pw + (mq * 16 + ml) * 32 + c0);
      uint2 bb = *(const uint2*)(Pw + (mq * 16 + ml) * 32 + c1);
      union { uint4 u; bh8 v; } pf;
      pf.u = make_uint4(a.x, a.y, bb.x, bb.y);
#pragma unroll
      for (int nd = 0; nd < 4; ++nd)
        oacc[mq][nd] = __builtin_amdgcn_mfma_f32_16x16x32_bf16(pf.v, vf[nd], oacc[mq][nd], 0, 0, 0);
    }
    __syncthreads();
  }

  // ---- epilogue: combine wk halves of l and O, normalize, store ----
#pragma unroll
  for (int nq = 0; nq < 4; ++nq) {
    li[nq] += __shfl_xor(li[nq], 16, 64);
    li[nq] += __shfl_xor(li[nq], 32, 64);
  }
  float* lbuf = (float*)(smem + 33280);  // [wq*2+wk][64 q]
  if (quad == 0) {
#pragma unroll
    for (int nq = 0; nq < 4; ++nq) lbuf[(wq * 2 + wk) * 64 + nq * 16 + ml] = li[nq];
  }
  float* obuf = (float*)smem;  // overlays Ks/Vs/Pw (dead); padded for banks
  if (wk == 0) {
#pragma unroll
    for (int mq = 0; mq < 4; ++mq)
#pragma unroll
      for (int nd = 0; nd < 4; ++nd)
        *(f4*)(obuf + wq * 4160 + 4 * ((mq * 4 + nd) * 65 + lane)) = oacc[mq][nd];
  }
  __syncthreads();
  if (wk == 1) {
#pragma unroll
    for (int mq = 0; mq < 4; ++mq) {
      float inv[4];
#pragma unroll
      for (int r = 0; r < 4; ++r) {
        int qq = mq * 16 + quad * 4 + r;
        inv[r] = 1.0f / (lbuf[(wq * 2) * 64 + qq] + lbuf[(wq * 2 + 1) * 64 + qq]);
      }
#pragma unroll
      for (int nd = 0; nd < 4; ++nd) {
        f4 part = *(const f4*)(obuf + wq * 4160 + 4 * ((mq * 4 + nd) * 65 + lane));
#pragma unroll
        for (int r = 0; r < 4; ++r) {
          int tl = q0 + mq * 16 + quad * 4 + r;
          int d = nd * 16 + ml;
          o[(((size_t)b * 2048 + tl) * 16 + h) * 64 + d] =
              f2bf((oacc[mq][nd][r] + part[r]) * inv[r]);
        }
      }
    }
  }
}

// ---------------- launch ----------------

extern "C" void kernel_launch(void* const* d_in, const int* in_sizes, int n_in,
                              void* d_out, int out_size, void* d_ws, size_t ws_size,
                              hipStream_t stream) {
  const float* x     = (const float*)d_in[0];
  const float* w_qkv = (const float*)d_in[1];
  const float* b_qkv = (const float*)d_in[2];
  const float* w_out = (const float*)d_in[3];
  const float* b_out = (const float*)d_in[4];
  float* out = (float*)d_out;

  u16* ws  = (u16*)d_ws;
  u16* xb  = ws;                                  // 8192*1024 (later reused for vt)
  u16* wqt = xb + (size_t)8192 * 1024;            // 3072*1024
  u16* wot = wqt + (size_t)3072 * 1024;           // 1024*1024
  u16* qb  = wot + (size_t)1024 * 1024;           // 64*2048*64
  u16* kb  = qb + (size_t)64 * 2048 * 64;
  u16* vb  = kb + (size_t)64 * 2048 * 64;
  u16* vtb = xb;   // xb dead after gemm_qkv
  u16* ob  = vb;   // v dead after transpose_b16

  cvt_f32_bf16<<<8192, 256, 0, stream>>>(x, xb, 8192 * 1024 / 4);
  transpose_cvt<<<dim3(96, 32), dim3(32, 32), 0, stream>>>(w_qkv, wqt, 1024, 3072);
  transpose_cvt<<<dim3(32, 32), dim3(32, 32), 0, stream>>>(w_out, wot, 1024, 1024);
  gemm_qkv<<<dim3(24, 64), 256, 0, stream>>>(xb, wqt, b_qkv, qb, kb, vb);
  transpose_b16<<<dim3(2, 64, 64), dim3(32, 32), 0, stream>>>(vb, vtb);
  attn<<<dim3(16, 64), 256, 0, stream>>>(qb, kb, vtb, ob);
  gemm_out<<<dim3(8, 64), 256, 0, stream>>>(ob, wot, b_out, out);
}